// Round 9
// baseline (148.299 us; speedup 1.0000x reference)
//
#include <hip/hip_runtime.h>
#include <math.h>

#define CN 4096
#define KDIM 256
#define ND 256   // H * D
#define NH 4
#define DD 64
#define NEG 0.2f
#define L2E 1.44269504f

typedef __attribute__((ext_vector_type(8))) short short8;   // 8 bf16 (4 VGPRs)
typedef __attribute__((ext_vector_type(4))) float floatx4;  // MFMA acc

union S8I4 { int i[4]; short8 s; };

__device__ inline unsigned bfbits_rne(float f) {
  unsigned u = __float_as_uint(f);
  u += 0x7fffu + ((u >> 16) & 1u);
  return u >> 16;
}
__device__ inline float bf2f(unsigned hi) { return __uint_as_float(hi << 16); }

// pack two fp32 -> one dword of 2 bf16 (truncation) via v_perm (verified R2-R8)
__device__ inline int pack2_trunc(float a, float b) {
  return (int)__builtin_amdgcn_perm(__float_as_uint(b), __float_as_uint(a), 0x07060302u);
}

// async global->LDS DMA: per-lane src, wave-uniform dst; lane L lands at dst + L*sz
#define GLDS(gp, lp, sz)                                                        \
  __builtin_amdgcn_global_load_lds(                                             \
      (const __attribute__((address_space(1))) void*)(gp),                      \
      (__attribute__((address_space(3))) void*)(lp), (sz), 0, 0)

// ---------------- Kernel 0: W -> bf16 hi/lo transposed [c][k]  (verified R4-R8)
__global__ __launch_bounds__(256) void k_wcvt(const float* __restrict__ W,
                                              unsigned short* __restrict__ WT_hi,
                                              unsigned short* __restrict__ WT_lo) {
  const int t = threadIdx.x;
  const int c = blockIdx.x * 4 + (t >> 6);
  const int k0 = (t & 63) * 4;
  unsigned h[4], l[4];
#pragma unroll
  for (int j = 0; j < 4; ++j) {
    const float w = W[(size_t)(k0 + j) * ND + c];
    h[j] = bfbits_rne(w);
    l[j] = bfbits_rne(w - bf2f(h[j]));
  }
  uint2 vh, vl;
  vh.x = h[0] | (h[1] << 16); vh.y = h[2] | (h[3] << 16);
  vl.x = l[0] | (l[1] << 16); vl.y = l[2] | (l[3] << 16);
  *(uint2*)&WT_hi[(size_t)c * KDIM + k0] = vh;
  *(uint2*)&WT_lo[(size_t)c * KDIM + k0] = vl;
}

// ---------------- Kernel 1 (merged): adj->bitmask stream + no-LDS MFMA GEMM
// (structure verified R8; Ecol now packed bf16 pairs for k_attn's LDS reads)
__global__ __launch_bounds__(256) void k_pre(const int* __restrict__ adj,
                                             unsigned char* __restrict__ mbits8,
                                             const float* __restrict__ x,
                                             const unsigned short* __restrict__ WT_hi,
                                             const unsigned short* __restrict__ WT_lo,
                                             const float* __restrict__ a_src,
                                             const float* __restrict__ a_dst,
                                             unsigned short* __restrict__ hT,
                                             float2* __restrict__ Erow,
                                             unsigned* __restrict__ Ecol_bf) {
  const int bx = blockIdx.x;
  const int t = threadIdx.x;
  if (bx >= 256) {
    const int w = t >> 6, lane = t & 63;
    const int row = (bx - 256) * 4 + w;
    const int4* __restrict__ src = (const int4*)(adj + (size_t)row * CN);
    unsigned char* __restrict__ dst = mbits8 + (size_t)row * 512;
#pragma unroll
    for (int it = 0; it < 8; ++it) {
      const int4 v0 = src[it * 128 + lane * 2];
      const int4 v1 = src[it * 128 + lane * 2 + 1];
      const unsigned b = (unsigned)(v0.x != 0)        | ((unsigned)(v0.y != 0) << 1) |
                         ((unsigned)(v0.z != 0) << 2) | ((unsigned)(v0.w != 0) << 3) |
                         ((unsigned)(v1.x != 0) << 4) | ((unsigned)(v1.y != 0) << 5) |
                         ((unsigned)(v1.z != 0) << 6) | ((unsigned)(v1.w != 0) << 7);
      dst[it * 64 + lane] = (unsigned char)b;
    }
    return;
  }
  // ---- gemm path (verified math R4-R8: hi/lo split, 3 MFMAs per frag-pair)
  const int lane = t & 63, ww = t >> 6;
  const int n = lane & 15, q = lane >> 4;
  const int head = bx >> 6;
  const int c0 = head * DD;
  const int i0 = (bx & 63) * 64 + ww * 16;
  const float* xr = x + (size_t)(i0 + n) * KDIM + q * 8;
  floatx4 acc[4] = {};
#pragma unroll 2
  for (int k0 = 0; k0 < KDIM; k0 += 32) {
    const float4 xa = *(const float4*)(xr + k0);
    const float4 xb = *(const float4*)(xr + k0 + 4);
    const float xs[8] = {xa.x, xa.y, xa.z, xa.w, xb.x, xb.y, xb.z, xb.w};
    S8I4 Ah, Al;
#pragma unroll
    for (int e = 0; e < 4; ++e) {
      const unsigned h0 = bfbits_rne(xs[2 * e]), h1 = bfbits_rne(xs[2 * e + 1]);
      const float r0 = xs[2 * e] - bf2f(h0), r1 = xs[2 * e + 1] - bf2f(h1);
      Ah.i[e] = (int)(h0 | (h1 << 16));
      Al.i[e] = (int)(bfbits_rne(r0) | (bfbits_rne(r1) << 16));
    }
#pragma unroll
    for (int tt = 0; tt < 4; ++tt) {
      const size_t boff = (size_t)(c0 + tt * 16 + n) * KDIM + k0 + q * 8;
      const short8 Bh = *(const short8*)(WT_hi + boff);
      const short8 Bl = *(const short8*)(WT_lo + boff);
      acc[tt] = __builtin_amdgcn_mfma_f32_16x16x32_bf16(Ah.s, Bh, acc[tt], 0, 0, 0);
      acc[tt] = __builtin_amdgcn_mfma_f32_16x16x32_bf16(Al.s, Bh, acc[tt], 0, 0, 0);
      acc[tt] = __builtin_amdgcn_mfma_f32_16x16x32_bf16(Ah.s, Bl, acc[tt], 0, 0, 0);
    }
  }
  // epilogue 1: hT[head][d = tt*16+n][i0 + q*4 + r] = bf16_rne(acc)
  unsigned short* hTb = hT + (size_t)head * DD * CN;
#pragma unroll
  for (int tt = 0; tt < 4; ++tt)
#pragma unroll
    for (int r = 0; r < 4; r += 2) {
      const unsigned d = bfbits_rne(acc[tt][r]) | (bfbits_rne(acc[tt][r + 1]) << 16);
      *(unsigned*)(hTb + (size_t)(tt * 16 + n) * CN + i0 + q * 4 + r) = d;
    }
  // epilogue 2: alpha dot-products -> exp2 pairs (max-trick, verified R7-R8)
  float ps[4] = {}, pd[4] = {};
#pragma unroll
  for (int tt = 0; tt < 4; ++tt) {
    const float as = a_src[head * DD + tt * 16 + n];
    const float ad = a_dst[head * DD + tt * 16 + n];
#pragma unroll
    for (int r = 0; r < 4; ++r) {
      ps[r] += acc[tt][r] * as;
      pd[r] += acc[tt][r] * ad;
    }
  }
#pragma unroll
  for (int off = 1; off < 16; off <<= 1)
#pragma unroll
    for (int r = 0; r < 4; ++r) {
      ps[r] += __shfl_xor(ps[r], off);
      pd[r] += __shfl_xor(pd[r], off);
    }
  if (n == 0) {
#pragma unroll
    for (int r = 0; r < 4; ++r) {
      const int i = i0 + q * 4 + r;
      const float as_ = ps[r] * L2E, ad_ = pd[r] * L2E;
      Erow[head * CN + i] = make_float2(__builtin_amdgcn_exp2f(as_),
                                        __builtin_amdgcn_exp2f(NEG * as_));
      // packed bf16 pair: lo = bf16(e^d), hi = bf16(e^{0.2 d})
      Ecol_bf[head * CN + i] = bfbits_rne(__builtin_amdgcn_exp2f(ad_)) |
                               (bfbits_rne(__builtin_amdgcn_exp2f(NEG * ad_)) << 16);
    }
  }
}

// ---------------- Kernel 2: fused masked softmax-numerator + attn@h, MFMA bf16.
// Grid (CN/64, NH, 4 j-quarters), 256 thr = 4 waves = 4 row-groups sharing a
// block-level 64-j chunk. Double-buffered cooperative GLDS staging with
// barriers (compiler-managed waitcnt; staging for c+1 issued between the two
// barriers so its vmcnt(0) drain lands at end-of-chunk). Waves own complete
// rows -> no in-block combine; partials (numerator+Z) written per j-quarter.
__global__ __launch_bounds__(256, 4) void k_attn(const unsigned short* __restrict__ hT,
                                                 const unsigned char* __restrict__ mbits8,
                                                 const float2* __restrict__ Erow,
                                                 const unsigned* __restrict__ Ecol_bf,
                                                 float* __restrict__ P,
                                                 float* __restrict__ Zb) {
  // per buf: [0,8192) hT tile [64 d][8 seg x 16B] (seg XOR d&7), [8192,8448) Ed
  __shared__ __align__(16) char smem[2][8448];
  const int t = threadIdx.x;
  const int lane = t & 63, ww = t >> 6;  // ww = row-group
  const int n = lane & 15, q = lane >> 4;
  const int head = blockIdx.y;
  const int jq = blockIdx.z;
  const int i0 = blockIdx.x * 64;
  const int jbase = jq * 1024;
  const unsigned short* __restrict__ hTb = hT + (size_t)head * DD * CN;
  const unsigned* __restrict__ ecb = Ecol_bf + (size_t)head * CN;
  const int myrow = i0 + ww * 16 + n;
  const float2 es = Erow[head * CN + myrow];  // (e^{s_i}, e^{0.2 s_i})
  const unsigned char* __restrict__ mrow = mbits8 + (size_t)myrow * 512;

  // lane-invariant swizzled GLDS src: lane L -> d=L>>3, seg=(L&7)^(L>>3)
  const unsigned hsw = (unsigned)(lane >> 3) * CN + (((lane & 7) ^ (lane >> 3)) * 8);

  short8 ONES;
#pragma unroll
  for (int u = 0; u < 8; ++u) ONES[u] = (short)0x3F80;  // bf16 1.0

  floatx4 acc[4] = {};
  floatx4 accz = {};

  auto STAGE = [&](int b, int j0) {
    char* base = smem[b];
    GLDS(hTb + (size_t)(ww * 16) * CN + hsw + j0, base + ww * 2048, 16);
    GLDS(hTb + (size_t)(ww * 16 + 8) * CN + hsw + j0, base + ww * 2048 + 1024, 16);
    if (ww == 0) GLDS(ecb + j0 + lane, base + 8192, 4);
  };

  unsigned m0 = mrow[(jbase >> 3) + q];
  unsigned m1 = mrow[(jbase >> 3) + q + 4];
  STAGE(0, jbase);
  for (int c = 0; c < 16; ++c) {
    const int j0 = jbase + c * 64;
    __syncthreads();  // buf c ready (staged DMAs drained at previous barrier)
    unsigned m0n = 0, m1n = 0;
    if (c < 15) {  // stage c+1 + prefetch its masks; overlaps compute below
      STAGE((c + 1) & 1, j0 + 64);
      m0n = mrow[((j0 + 64) >> 3) + q];
      m1n = mrow[((j0 + 64) >> 3) + q + 4];
    }
    const char* base = smem[c & 1];
#pragma unroll
    for (int kf = 0; kf < 2; ++kf) {
      short8 B[4];
#pragma unroll
      for (int tt = 0; tt < 4; ++tt)
        B[tt] = *(const short8*)(base + (tt * 16 + n) * 128 +
                                 (((kf * 4 + q) ^ (n & 7)) << 4));
      const uint4 e0 = *(const uint4*)(base + 8192 + (kf * 32 + q * 8) * 4);
      const uint4 e1 = *(const uint4*)(base + 8192 + (kf * 32 + q * 8) * 4 + 16);
      const unsigned ev[8] = {e0.x, e0.y, e0.z, e0.w, e1.x, e1.y, e1.z, e1.w};
      const unsigned mb = kf ? m1 : m0;
      float fv[8];
#pragma unroll
      for (int e = 0; e < 8; ++e) {
        const float Ed = __uint_as_float(ev[e] << 16);
        const float Ed2 = __uint_as_float(ev[e] & 0xffff0000u);
        const float w = fmaxf(es.x * Ed, es.y * Ed2);  // exp(leaky(s+d))
        fv[e] = ((mb >> e) & 1u) ? w : 0.0f;           // adjacency mask
      }
      S8I4 A;
#pragma unroll
      for (int e = 0; e < 4; ++e) A.i[e] = pack2_trunc(fv[2 * e], fv[2 * e + 1]);
      accz = __builtin_amdgcn_mfma_f32_16x16x32_bf16(A.s, ONES, accz, 0, 0, 0);
#pragma unroll
      for (int tt = 0; tt < 4; ++tt)
        acc[tt] = __builtin_amdgcn_mfma_f32_16x16x32_bf16(A.s, B[tt], acc[tt], 0, 0, 0);
    }
    m0 = m0n; m1 = m1n;
    __syncthreads();  // drains staging of c+1; frees buf c for iter c+1's STAGE
  }

  // partial write: rows complete per wave; C/D row = q*4+r, col = tt*16+n
  float* Pp = P + ((size_t)(jq * NH + head) * CN + i0) * DD;
  float* Zp = Zb + (size_t)(jq * NH + head) * CN + i0;
#pragma unroll
  for (int r = 0; r < 4; ++r) {
    const int rl = ww * 16 + q * 4 + r;
#pragma unroll
    for (int tt = 0; tt < 4; ++tt) Pp[(size_t)rl * DD + tt * 16 + n] = acc[tt][r];
    if (n == 0) Zp[rl] = accz[r];
  }
}

// ---------------- Kernel 3: combine 4 j-quarter partials, divide by Z
__global__ __launch_bounds__(256) void k_fin(const float* __restrict__ P,
                                             const float* __restrict__ Zb,
                                             float* __restrict__ out) {
  const int i = blockIdx.x;
  const int t = threadIdx.x;
  const int head = t >> 6, d = t & 63;
  float num = 0.f, z = 0.f;
#pragma unroll
  for (int jqq = 0; jqq < 4; ++jqq) {
    num += P[((size_t)(jqq * NH + head) * CN + i) * DD + d];
    z += Zb[(size_t)(jqq * NH + head) * CN + i];
  }
  out[(size_t)i * ND + head * DD + d] = num / z;
}

extern "C" void kernel_launch(void* const* d_in, const int* in_sizes, int n_in,
                              void* d_out, int out_size, void* d_ws, size_t ws_size,
                              hipStream_t stream) {
  const float* x = (const float*)d_in[0];
  const int* adj = (const int*)d_in[1];
  const float* W = (const float*)d_in[2];
  const float* a_src = (const float*)d_in[3];
  const float* a_dst = (const float*)d_in[4];
  float* out = (float*)d_out;

  unsigned short* hT = (unsigned short*)d_ws;                          // 2 MB
  float2* Erow = (float2*)(hT + (size_t)NH * DD * CN);                 // 128 KB
  unsigned* Ecol_bf = (unsigned*)(Erow + (size_t)NH * CN);             // 64 KB
  unsigned short* WT_hi = (unsigned short*)(Ecol_bf + (size_t)NH * CN);  // 128 KB
  unsigned short* WT_lo = WT_hi + (size_t)ND * KDIM;                   // 128 KB
  unsigned char* mbits8 = (unsigned char*)(WT_lo + (size_t)ND * KDIM); // 2 MB
  float* P = (float*)(mbits8 + (size_t)CN * 512);                      // 16.78 MB
  float* Zb = P + (size_t)4 * NH * CN * DD;                            // 256 KB

  k_wcvt<<<dim3(ND / 4), 256, 0, stream>>>(W, WT_hi, WT_lo);
  k_pre<<<dim3(256 + CN / 4), 256, 0, stream>>>(adj, mbits8, x, WT_hi, WT_lo,
                                                a_src, a_dst, hT, Erow, Ecol_bf);
  k_attn<<<dim3(CN / 64, NH, 4), 256, 0, stream>>>(hT, mbits8, Erow, Ecol_bf, P, Zb);
  k_fin<<<dim3(CN), 256, 0, stream>>>(P, Zb, out);
}

// Round 10
// 136.026 us; speedup vs baseline: 1.0902x; 1.0902x over previous
//
#include <hip/hip_runtime.h>
#include <math.h>

#define CN 4096
#define KDIM 256
#define ND 256   // H * D
#define NH 4
#define DD 64
#define NEG 0.2f
#define L2E 1.44269504f

typedef __attribute__((ext_vector_type(8))) short short8;   // 8 bf16 (4 VGPRs)
typedef __attribute__((ext_vector_type(4))) float floatx4;  // MFMA acc

union S8I4 { int i[4]; short8 s; };

__device__ inline unsigned bfbits_rne(float f) {
  unsigned u = __float_as_uint(f);
  u += 0x7fffu + ((u >> 16) & 1u);
  return u >> 16;
}
__device__ inline float bf2f(unsigned hi) { return __uint_as_float(hi << 16); }

// pack two fp32 -> one dword of 2 bf16 (truncation) via v_perm (verified R2-R9)
__device__ inline int pack2_trunc(float a, float b) {
  return (int)__builtin_amdgcn_perm(__float_as_uint(b), __float_as_uint(a), 0x07060302u);
}

// async global->LDS DMA: per-lane src, wave-uniform dst; lane L lands at dst + L*sz
#define GLDS(gp, lp, sz)                                                        \
  __builtin_amdgcn_global_load_lds(                                             \
      (const __attribute__((address_space(1))) void*)(gp),                      \
      (__attribute__((address_space(3))) void*)(lp), (sz), 0, 0)

// ---------------- Kernel 1 (merged): adj byte-pack stream + LDS-W MFMA GEMM.
// bx >= 256: 4 adj rows, wave = 1 row; lane packs 8 ints (2x dwordx4) into one
//            byte (verified R8) — fat loads, no ballot.
// bx < 256:  GEMM block (head = bx>>6, i-tile (bx&63)*64): stages its fp32 W
//            slice -> bf16 hi/lo padded LDS (k_wcvt folded in), then the
//            R5-verified LDS GEMM main loop + R8-verified epilogue
//            (hT bf16 + Erow/Ecol exp2 pairs for the max-trick).
__global__ __launch_bounds__(256, 2) void k_pre(const int* __restrict__ adj,
                                                unsigned char* __restrict__ mbits8,
                                                const float* __restrict__ x,
                                                const float* __restrict__ W,
                                                const float* __restrict__ a_src,
                                                const float* __restrict__ a_dst,
                                                unsigned short* __restrict__ hT,
                                                float2* __restrict__ Erow,
                                                float2* __restrict__ Ecol) {
  __shared__ __align__(16) unsigned short Whi_s[64 * 264];  // [c][k], pad 264
  __shared__ __align__(16) unsigned short Wlo_s[64 * 264];
  const int bx = blockIdx.x;
  const int t = threadIdx.x;
  if (bx >= 256) {
    const int w = t >> 6, lane = t & 63;
    const int row = (bx - 256) * 4 + w;
    const int4* __restrict__ src = (const int4*)(adj + (size_t)row * CN);
    unsigned char* __restrict__ dst = mbits8 + (size_t)row * 512;
#pragma unroll
    for (int it = 0; it < 8; ++it) {
      const int4 v0 = src[it * 128 + lane * 2];
      const int4 v1 = src[it * 128 + lane * 2 + 1];
      const unsigned b = (unsigned)(v0.x != 0)        | ((unsigned)(v0.y != 0) << 1) |
                         ((unsigned)(v0.z != 0) << 2) | ((unsigned)(v0.w != 0) << 3) |
                         ((unsigned)(v1.x != 0) << 4) | ((unsigned)(v1.y != 0) << 5) |
                         ((unsigned)(v1.z != 0) << 6) | ((unsigned)(v1.w != 0) << 7);
      dst[it * 64 + lane] = (unsigned char)b;
    }
    return;
  }
  // ---- GEMM path
  const int lane = t & 63, ww = t >> 6;
  const int n = lane & 15, q = lane >> 4;
  const int head = bx >> 6;
  const int c0 = head * DD;
  const int i0 = (bx & 63) * 64 + ww * 16;
  // stage + convert W fp32 -> bf16 hi/lo LDS (one-time; coalesced 256B rows)
  {
    const int c = t & 63, kb = t >> 6;
    const float* Wc = W + c0 + c;
#pragma unroll 8
    for (int p = 0; p < 64; ++p) {
      const int k = p * 4 + kb;
      const float w = Wc[(size_t)k * ND];
      const unsigned hi = bfbits_rne(w);
      const unsigned lo = bfbits_rne(w - bf2f(hi));
      Whi_s[c * 264 + k] = (unsigned short)hi;
      Wlo_s[c * 264 + k] = (unsigned short)lo;
    }
  }
  const float* xr = x + (size_t)(i0 + n) * KDIM + q * 8;
  float4 xa = *(const float4*)(xr);
  float4 xb = *(const float4*)(xr + 4);
  __syncthreads();
  floatx4 acc[4] = {};
  for (int k0 = 0; k0 < KDIM; k0 += 32) {
    const float xs[8] = {xa.x, xa.y, xa.z, xa.w, xb.x, xb.y, xb.z, xb.w};
    if (k0 + 32 < KDIM) {  // prefetch next x chunk
      xa = *(const float4*)(xr + k0 + 32);
      xb = *(const float4*)(xr + k0 + 36);
    }
    S8I4 Ah, Al;
#pragma unroll
    for (int e = 0; e < 4; ++e) {
      const unsigned h0 = bfbits_rne(xs[2 * e]), h1 = bfbits_rne(xs[2 * e + 1]);
      const float r0 = xs[2 * e] - bf2f(h0), r1 = xs[2 * e + 1] - bf2f(h1);
      Ah.i[e] = (int)(h0 | (h1 << 16));
      Al.i[e] = (int)(bfbits_rne(r0) | (bfbits_rne(r1) << 16));
    }
#pragma unroll
    for (int tt = 0; tt < 4; ++tt) {
      const int boff = (tt * 16 + n) * 264 + k0 + q * 8;
      const short8 Bh = *(const short8*)&Whi_s[boff];
      const short8 Bl = *(const short8*)&Wlo_s[boff];
      acc[tt] = __builtin_amdgcn_mfma_f32_16x16x32_bf16(Ah.s, Bh, acc[tt], 0, 0, 0);
      acc[tt] = __builtin_amdgcn_mfma_f32_16x16x32_bf16(Al.s, Bh, acc[tt], 0, 0, 0);
      acc[tt] = __builtin_amdgcn_mfma_f32_16x16x32_bf16(Ah.s, Bl, acc[tt], 0, 0, 0);
    }
  }
  // epilogue 1: hT[head][d = tt*16+n][i0 + q*4 + r] = bf16_rne(acc)
  unsigned short* hTb = hT + (size_t)head * DD * CN;
#pragma unroll
  for (int tt = 0; tt < 4; ++tt)
#pragma unroll
    for (int r = 0; r < 4; r += 2) {
      const unsigned d = bfbits_rne(acc[tt][r]) | (bfbits_rne(acc[tt][r + 1]) << 16);
      *(unsigned*)(hTb + (size_t)(tt * 16 + n) * CN + i0 + q * 4 + r) = d;
    }
  // epilogue 2: alpha dot-products -> exp2 pairs (max-trick, verified R7-R8)
  float ps[4] = {}, pd[4] = {};
#pragma unroll
  for (int tt = 0; tt < 4; ++tt) {
    const float as = a_src[head * DD + tt * 16 + n];
    const float ad = a_dst[head * DD + tt * 16 + n];
#pragma unroll
    for (int r = 0; r < 4; ++r) {
      ps[r] += acc[tt][r] * as;
      pd[r] += acc[tt][r] * ad;
    }
  }
#pragma unroll
  for (int off = 1; off < 16; off <<= 1)
#pragma unroll
    for (int r = 0; r < 4; ++r) {
      ps[r] += __shfl_xor(ps[r], off);
      pd[r] += __shfl_xor(pd[r], off);
    }
  if (n == 0) {
#pragma unroll
    for (int r = 0; r < 4; ++r) {
      const int i = i0 + q * 4 + r;
      const float as_ = ps[r] * L2E, ad_ = pd[r] * L2E;
      Erow[head * CN + i] = make_float2(__builtin_amdgcn_exp2f(as_),
                                        __builtin_amdgcn_exp2f(NEG * as_));
      Ecol[head * CN + i] = make_float2(__builtin_amdgcn_exp2f(ad_),
                                        __builtin_amdgcn_exp2f(NEG * ad_));
    }
  }
}

// ---------------- Kernel 2: fused masked softmax + attn@h, MFMA bf16
// (verbatim R8 kernel — passed, absmax 0.00195).
// w_ij = exp(leaky(s_i+d_j)) = max(Es_i*Ed_j, Es2_i*Ed2_j)  — no exp in loop.
__global__ __launch_bounds__(512, 4) void k_attn(const unsigned short* __restrict__ hT,
                                                 const unsigned* __restrict__ mbits32,
                                                 const float2* __restrict__ Erow,
                                                 const float2* __restrict__ Ecol,
                                                 float* __restrict__ out) {
  // per wave, per buf: [0,4096) hT tile [64 d][32 j] (16B-seg XOR-swizzled),
  //                    [4096,4352) mask dwords, [4352,4608) Ecol floats
  __shared__ __align__(16) char smem[8 * 2 * 4608];  // 73,728 B
  const int t = threadIdx.x;
  const int lane = t & 63, ww = t >> 6;
  const int n = lane & 15, q = lane >> 4;
  const int head = blockIdx.y;
  const int i0 = blockIdx.x * 32;
  const unsigned short* __restrict__ hTb = hT + (size_t)head * DD * CN;
  const float* __restrict__ ecf = (const float*)(Ecol + (size_t)head * CN);
  const int jbase = ww * 512;  // this wave's j-eighth

  const float2 es0 = Erow[head * CN + i0 + n];       // rows i0+n      (rg 0)
  const float2 es1 = Erow[head * CN + i0 + 16 + n];  // rows i0+16+n   (rg 1)

  // per-lane invariant DMA source offsets (swizzle verified R6)
  const unsigned hoff =
      (unsigned)(lane >> 2) * CN + (((lane & 3) ^ ((lane >> 3) & 3)) * 8);
  const unsigned mrow = (unsigned)(i0 + (lane & 31)) * 128;  // dwords/row = 128
  char* const wbase = smem + ww * 2 * 4608;

  short8 ONES;
#pragma unroll
  for (int u = 0; u < 8; ++u) ONES[u] = (short)0x3F80;  // bf16 1.0

  floatx4 acc[2][4] = {};
  floatx4 accz[2] = {};

  auto ISSUE = [&](int b, int j0) {
    char* base = wbase + b * 4608;
#pragma unroll
    for (int g = 0; g < 4; ++g)
      GLDS(hTb + (size_t)(g * 16) * CN + hoff + j0, base + g * 1024, 16);
    GLDS(mbits32 + mrow + (j0 >> 5), base + 4096, 4);
    GLDS(ecf + j0 * 2 + lane, base + 4352, 4);  // 32 j x (Ed,Ed2)
  };

  ISSUE(0, jbase);
  for (int c = 0; c < 16; ++c) {
    if (c < 15) {
      ISSUE((c + 1) & 1, jbase + (c + 1) * 32);
      asm volatile("s_waitcnt vmcnt(6)" ::: "memory");  // chunk c done, c+1 flying
    } else {
      asm volatile("s_waitcnt vmcnt(0)" ::: "memory");
    }
    const char* base = wbase + (c & 1) * 4608;
    // B fragments: d = tt*16+n, k = q*8+e; slot XOR matches DMA swizzle (R6)
    short8 B[4];
#pragma unroll
    for (int tt = 0; tt < 4; ++tt)
      B[tt] = *(const short8*)(base + (tt * 16 + n) * 64 +
                               ((q ^ ((n >> 1) & 3)) << 4));
    const unsigned m0 = *(const unsigned*)(base + 4096 + n * 4);
    const unsigned m1 = *(const unsigned*)(base + 4096 + (16 + n) * 4);
    const unsigned mb0 = (m0 >> (q * 8)) & 255u;
    const unsigned mb1 = (m1 >> (q * 8)) & 255u;
    const float4* adl4 = (const float4*)(base + 4352);
    S8I4 A[2];
#pragma unroll
    for (int g = 0; g < 4; ++g) {
      // v = {Ed(j=q8+2g), Ed2(j=q8+2g), Ed(j=q8+2g+1), Ed2(j=q8+2g+1)}
      const float4 v = adl4[q * 4 + g];
#pragma unroll
      for (int rg = 0; rg < 2; ++rg) {
        const float2 es = rg ? es1 : es0;
        const unsigned mb = rg ? mb1 : mb0;
        float w0 = fmaxf(es.x * v.x, es.y * v.y);
        float w1 = fmaxf(es.x * v.z, es.y * v.w);
        w0 = ((mb >> (2 * g)) & 1u) ? w0 : 0.0f;
        w1 = ((mb >> (2 * g + 1)) & 1u) ? w1 : 0.0f;
        A[rg].i[g] = pack2_trunc(w0, w1);
      }
    }
#pragma unroll
    for (int rg = 0; rg < 2; ++rg) {
      accz[rg] = __builtin_amdgcn_mfma_f32_16x16x32_bf16(A[rg].s, ONES, accz[rg], 0, 0, 0);
#pragma unroll
      for (int tt = 0; tt < 4; ++tt)
        acc[rg][tt] =
            __builtin_amdgcn_mfma_f32_16x16x32_bf16(A[rg].s, B[tt], acc[rg][tt], 0, 0, 0);
    }
  }

  // ---- 8-way combine through LDS (verified R6-R8; DMAs drained above)
  __syncthreads();
  float* red = (float*)smem;  // [7 waves][40 frags][64 lanes]
  if (ww > 0) {
    float* rb = red + (ww - 1) * 2560;
#pragma unroll
    for (int rg = 0; rg < 2; ++rg) {
#pragma unroll
      for (int tt = 0; tt < 4; ++tt)
#pragma unroll
        for (int r = 0; r < 4; ++r)
          rb[(rg * 20 + tt * 4 + r) * 64 + lane] = acc[rg][tt][r];
#pragma unroll
      for (int r = 0; r < 4; ++r) rb[(rg * 20 + 16 + r) * 64 + lane] = accz[rg][r];
    }
  }
  __syncthreads();
  if (ww == 0) {
#pragma unroll
    for (int s = 0; s < 7; ++s) {
      const float* rb = red + s * 2560;
#pragma unroll
      for (int rg = 0; rg < 2; ++rg) {
#pragma unroll
        for (int tt = 0; tt < 4; ++tt)
#pragma unroll
          for (int r = 0; r < 4; ++r)
            acc[rg][tt][r] += rb[(rg * 20 + tt * 4 + r) * 64 + lane];
#pragma unroll
        for (int r = 0; r < 4; ++r) accz[rg][r] += rb[(rg * 20 + 16 + r) * 64 + lane];
      }
    }
    // epilogue: C/D row = q*4+r, col = tt*16+n (verified R2-R8)
#pragma unroll
    for (int rg = 0; rg < 2; ++rg)
#pragma unroll
      for (int r = 0; r < 4; ++r) {
        const float iz = 1.0f / accz[rg][r];
        float* orow = out + (size_t)(i0 + rg * 16 + q * 4 + r) * ND + head * DD + n;
#pragma unroll
        for (int tt = 0; tt < 4; ++tt) orow[tt * 16] = acc[rg][tt][r] * iz;
      }
  }
}

extern "C" void kernel_launch(void* const* d_in, const int* in_sizes, int n_in,
                              void* d_out, int out_size, void* d_ws, size_t ws_size,
                              hipStream_t stream) {
  const float* x = (const float*)d_in[0];
  const int* adj = (const int*)d_in[1];
  const float* W = (const float*)d_in[2];
  const float* a_src = (const float*)d_in[3];
  const float* a_dst = (const float*)d_in[4];
  float* out = (float*)d_out;

  unsigned short* hT = (unsigned short*)d_ws;                     // 2 MB
  float2* Erow = (float2*)(hT + (size_t)NH * DD * CN);            // 128 KB
  float2* Ecol = Erow + (size_t)NH * CN;                          // 128 KB
  unsigned char* mbits8 = (unsigned char*)(Ecol + (size_t)NH * CN);  // 2 MB

  k_pre<<<dim3(256 + CN / 4), 256, 0, stream>>>(adj, mbits8, x, W,
                                                a_src, a_dst, hT, Erow, Ecol);
  k_attn<<<dim3(CN / 32, NH), 512, 0, stream>>>(hT, (const unsigned*)mbits8,
                                                Erow, Ecol, out);
}

// Round 12
// 132.487 us; speedup vs baseline: 1.1193x; 1.0267x over previous
//
#include <hip/hip_runtime.h>
#include <math.h>

#define CN 4096
#define KDIM 256
#define ND 256   // H * D
#define NH 4
#define DD 64
#define NEG 0.2f
#define L2E 1.44269504f

typedef __attribute__((ext_vector_type(8))) short short8;   // 8 bf16 (4 VGPRs)
typedef __attribute__((ext_vector_type(4))) float floatx4;  // MFMA acc

union S8I4 { int i[4]; short8 s; };

__device__ inline unsigned bfbits_rne(float f) {
  unsigned u = __float_as_uint(f);
  u += 0x7fffu + ((u >> 16) & 1u);
  return u >> 16;
}
__device__ inline float bf2f(unsigned hi) { return __uint_as_float(hi << 16); }

// pack two fp32 -> one dword of 2 bf16 (truncation) via v_perm (verified R2-R10)
__device__ inline int pack2_trunc(float a, float b) {
  return (int)__builtin_amdgcn_perm(__float_as_uint(b), __float_as_uint(a), 0x07060302u);
}

// async global->LDS DMA: per-lane src, wave-uniform dst; lane L lands at dst + L*sz
// CONTRACT (learned R11): compiler inserts NO wait between this and dependent
// ds_reads — an explicit s_waitcnt vmcnt is mandatory before consuming.
#define GLDS(gp, lp, sz)                                                        \
  __builtin_amdgcn_global_load_lds(                                             \
      (const __attribute__((address_space(1))) void*)(gp),                      \
      (__attribute__((address_space(3))) void*)(lp), (sz), 0, 0)

// ---------------- Kernel 1 (merged): adj byte-pack stream + LDS-W MFMA GEMM.
// (verbatim R10 — verified)
__global__ __launch_bounds__(256, 2) void k_pre(const int* __restrict__ adj,
                                                unsigned char* __restrict__ mbits8,
                                                const float* __restrict__ x,
                                                const float* __restrict__ W,
                                                const float* __restrict__ a_src,
                                                const float* __restrict__ a_dst,
                                                unsigned short* __restrict__ hT,
                                                float2* __restrict__ Erow,
                                                float2* __restrict__ Ecol) {
  __shared__ __align__(16) unsigned short Whi_s[64 * 264];  // [c][k], pad 264
  __shared__ __align__(16) unsigned short Wlo_s[64 * 264];
  const int bx = blockIdx.x;
  const int t = threadIdx.x;
  if (bx >= 256) {
    const int w = t >> 6, lane = t & 63;
    const int row = (bx - 256) * 4 + w;
    const int4* __restrict__ src = (const int4*)(adj + (size_t)row * CN);
    unsigned char* __restrict__ dst = mbits8 + (size_t)row * 512;
#pragma unroll
    for (int it = 0; it < 8; ++it) {
      const int4 v0 = src[it * 128 + lane * 2];
      const int4 v1 = src[it * 128 + lane * 2 + 1];
      const unsigned b = (unsigned)(v0.x != 0)        | ((unsigned)(v0.y != 0) << 1) |
                         ((unsigned)(v0.z != 0) << 2) | ((unsigned)(v0.w != 0) << 3) |
                         ((unsigned)(v1.x != 0) << 4) | ((unsigned)(v1.y != 0) << 5) |
                         ((unsigned)(v1.z != 0) << 6) | ((unsigned)(v1.w != 0) << 7);
      dst[it * 64 + lane] = (unsigned char)b;
    }
    return;
  }
  // ---- GEMM path (verified R4-R10)
  const int lane = t & 63, ww = t >> 6;
  const int n = lane & 15, q = lane >> 4;
  const int head = bx >> 6;
  const int c0 = head * DD;
  const int i0 = (bx & 63) * 64 + ww * 16;
  {
    const int c = t & 63, kb = t >> 6;
    const float* Wc = W + c0 + c;
#pragma unroll 8
    for (int p = 0; p < 64; ++p) {
      const int k = p * 4 + kb;
      const float w = Wc[(size_t)k * ND];
      const unsigned hi = bfbits_rne(w);
      const unsigned lo = bfbits_rne(w - bf2f(hi));
      Whi_s[c * 264 + k] = (unsigned short)hi;
      Wlo_s[c * 264 + k] = (unsigned short)lo;
    }
  }
  const float* xr = x + (size_t)(i0 + n) * KDIM + q * 8;
  float4 xa = *(const float4*)(xr);
  float4 xb = *(const float4*)(xr + 4);
  __syncthreads();
  floatx4 acc[4] = {};
  for (int k0 = 0; k0 < KDIM; k0 += 32) {
    const float xs[8] = {xa.x, xa.y, xa.z, xa.w, xb.x, xb.y, xb.z, xb.w};
    if (k0 + 32 < KDIM) {
      xa = *(const float4*)(xr + k0 + 32);
      xb = *(const float4*)(xr + k0 + 36);
    }
    S8I4 Ah, Al;
#pragma unroll
    for (int e = 0; e < 4; ++e) {
      const unsigned h0 = bfbits_rne(xs[2 * e]), h1 = bfbits_rne(xs[2 * e + 1]);
      const float r0 = xs[2 * e] - bf2f(h0), r1 = xs[2 * e + 1] - bf2f(h1);
      Ah.i[e] = (int)(h0 | (h1 << 16));
      Al.i[e] = (int)(bfbits_rne(r0) | (bfbits_rne(r1) << 16));
    }
#pragma unroll
    for (int tt = 0; tt < 4; ++tt) {
      const int boff = (tt * 16 + n) * 264 + k0 + q * 8;
      const short8 Bh = *(const short8*)&Whi_s[boff];
      const short8 Bl = *(const short8*)&Wlo_s[boff];
      acc[tt] = __builtin_amdgcn_mfma_f32_16x16x32_bf16(Ah.s, Bh, acc[tt], 0, 0, 0);
      acc[tt] = __builtin_amdgcn_mfma_f32_16x16x32_bf16(Al.s, Bh, acc[tt], 0, 0, 0);
      acc[tt] = __builtin_amdgcn_mfma_f32_16x16x32_bf16(Ah.s, Bl, acc[tt], 0, 0, 0);
    }
  }
  unsigned short* hTb = hT + (size_t)head * DD * CN;
#pragma unroll
  for (int tt = 0; tt < 4; ++tt)
#pragma unroll
    for (int r = 0; r < 4; r += 2) {
      const unsigned d = bfbits_rne(acc[tt][r]) | (bfbits_rne(acc[tt][r + 1]) << 16);
      *(unsigned*)(hTb + (size_t)(tt * 16 + n) * CN + i0 + q * 4 + r) = d;
    }
  float ps[4] = {}, pd[4] = {};
#pragma unroll
  for (int tt = 0; tt < 4; ++tt) {
    const float as = a_src[head * DD + tt * 16 + n];
    const float ad = a_dst[head * DD + tt * 16 + n];
#pragma unroll
    for (int r = 0; r < 4; ++r) {
      ps[r] += acc[tt][r] * as;
      pd[r] += acc[tt][r] * ad;
    }
  }
#pragma unroll
  for (int off = 1; off < 16; off <<= 1)
#pragma unroll
    for (int r = 0; r < 4; ++r) {
      ps[r] += __shfl_xor(ps[r], off);
      pd[r] += __shfl_xor(pd[r], off);
    }
  if (n == 0) {
#pragma unroll
    for (int r = 0; r < 4; ++r) {
      const int i = i0 + q * 4 + r;
      const float as_ = ps[r] * L2E, ad_ = pd[r] * L2E;
      Erow[head * CN + i] = make_float2(__builtin_amdgcn_exp2f(as_),
                                        __builtin_amdgcn_exp2f(NEG * as_));
      Ecol[head * CN + i] = make_float2(__builtin_amdgcn_exp2f(ad_),
                                        __builtin_amdgcn_exp2f(NEG * ad_));
    }
  }
}

// ---------------- Kernel 2: fused masked softmax + attn@h, MFMA bf16.
// Consume-then-issue double buffer (R11) + the mandatory explicit drain:
//   iter c:  s_waitcnt vmcnt(0)   <- only buf c's 6 DMAs outstanding; they had
//                                    all of chunk c-1's compute to land
//            read buf c -> regs
//            ISSUE(c+1)           <- flies across chunk c's compute
//            compute chunk c
__global__ __launch_bounds__(512, 4) void k_attn(const unsigned short* __restrict__ hT,
                                                 const unsigned* __restrict__ mbits32,
                                                 const float2* __restrict__ Erow,
                                                 const float2* __restrict__ Ecol,
                                                 float* __restrict__ out) {
  // per wave, per buf: [0,4096) hT tile [64 d][32 j] (16B-seg XOR-swizzled),
  //                    [4096,4352) mask dwords, [4352,4608) Ecol floats
  __shared__ __align__(16) char smem[8 * 2 * 4608];  // 73,728 B
  const int t = threadIdx.x;
  const int lane = t & 63, ww = t >> 6;
  const int n = lane & 15, q = lane >> 4;
  const int head = blockIdx.y;
  const int i0 = blockIdx.x * 32;
  const unsigned short* __restrict__ hTb = hT + (size_t)head * DD * CN;
  const float* __restrict__ ecf = (const float*)(Ecol + (size_t)head * CN);
  const int jbase = ww * 512;  // this wave's j-eighth

  const float2 es0 = Erow[head * CN + i0 + n];       // rows i0+n      (rg 0)
  const float2 es1 = Erow[head * CN + i0 + 16 + n];  // rows i0+16+n   (rg 1)

  // per-lane invariant DMA source offsets (swizzle verified R6-R10)
  const unsigned hoff =
      (unsigned)(lane >> 2) * CN + (((lane & 3) ^ ((lane >> 3) & 3)) * 8);
  const unsigned mrow = (unsigned)(i0 + (lane & 31)) * 128;  // dwords/row = 128
  char* const wbase = smem + ww * 2 * 4608;

  short8 ONES;
#pragma unroll
  for (int u = 0; u < 8; ++u) ONES[u] = (short)0x3F80;  // bf16 1.0

  floatx4 acc[2][4] = {};
  floatx4 accz[2] = {};

  auto ISSUE = [&](int b, int j0) {
    char* base = wbase + b * 4608;
#pragma unroll
    for (int g = 0; g < 4; ++g)
      GLDS(hTb + (size_t)(g * 16) * CN + hoff + j0, base + g * 1024, 16);
    GLDS(mbits32 + mrow + (j0 >> 5), base + 4096, 4);
    GLDS(ecf + j0 * 2 + lane, base + 4352, 4);  // 32 j x (Ed,Ed2)
  };

  ISSUE(0, jbase);
  for (int c = 0; c < 16; ++c) {
    // ---- drain buf c's DMAs (the only ones outstanding at this point)
    asm volatile("s_waitcnt vmcnt(0)" ::: "memory");
    const char* base = wbase + (c & 1) * 4608;
    // ---- consume: read ALL of buffer c into registers
    short8 B[4];
#pragma unroll
    for (int tt = 0; tt < 4; ++tt)
      B[tt] = *(const short8*)(base + (tt * 16 + n) * 64 +
                               ((q ^ ((n >> 1) & 3)) << 4));
    const unsigned m0 = *(const unsigned*)(base + 4096 + n * 4);
    const unsigned m1 = *(const unsigned*)(base + 4096 + (16 + n) * 4);
    const float4* adl4 = (const float4*)(base + 4352);
    float4 vv[4];
#pragma unroll
    for (int g = 0; g < 4; ++g) vv[g] = adl4[q * 4 + g];
    // LDS reads must complete before the overwriting stage of c+1 is issued
    asm volatile("s_waitcnt lgkmcnt(0)" ::: "memory");
    // ---- issue: stage chunk c+1; flies across chunk c's compute
    if (c < 15) ISSUE((c + 1) & 1, jbase + (c + 1) * 32);
    // ---- compute chunk c from registers
    const unsigned mb0 = (m0 >> (q * 8)) & 255u;
    const unsigned mb1 = (m1 >> (q * 8)) & 255u;
    S8I4 A[2];
#pragma unroll
    for (int g = 0; g < 4; ++g) {
      const float4 v = vv[g];
#pragma unroll
      for (int rg = 0; rg < 2; ++rg) {
        const float2 es = rg ? es1 : es0;
        const unsigned mb = rg ? mb1 : mb0;
        float w0 = fmaxf(es.x * v.x, es.y * v.y);
        float w1 = fmaxf(es.x * v.z, es.y * v.w);
        w0 = ((mb >> (2 * g)) & 1u) ? w0 : 0.0f;
        w1 = ((mb >> (2 * g + 1)) & 1u) ? w1 : 0.0f;
        A[rg].i[g] = pack2_trunc(w0, w1);
      }
    }
#pragma unroll
    for (int rg = 0; rg < 2; ++rg) {
      accz[rg] = __builtin_amdgcn_mfma_f32_16x16x32_bf16(A[rg].s, ONES, accz[rg], 0, 0, 0);
#pragma unroll
      for (int tt = 0; tt < 4; ++tt)
        acc[rg][tt] =
            __builtin_amdgcn_mfma_f32_16x16x32_bf16(A[rg].s, B[tt], acc[rg][tt], 0, 0, 0);
    }
  }

  // ---- 8-way combine through LDS (verified R6-R10; iter 15 issued no DMAs)
  __syncthreads();
  float* red = (float*)smem;  // [7 waves][40 frags][64 lanes]
  if (ww > 0) {
    float* rb = red + (ww - 1) * 2560;
#pragma unroll
    for (int rg = 0; rg < 2; ++rg) {
#pragma unroll
      for (int tt = 0; tt < 4; ++tt)
#pragma unroll
        for (int r = 0; r < 4; ++r)
          rb[(rg * 20 + tt * 4 + r) * 64 + lane] = acc[rg][tt][r];
#pragma unroll
      for (int r = 0; r < 4; ++r) rb[(rg * 20 + 16 + r) * 64 + lane] = accz[rg][r];
    }
  }
  __syncthreads();
  if (ww == 0) {
#pragma unroll
    for (int s = 0; s < 7; ++s) {
      const float* rb = red + s * 2560;
#pragma unroll
      for (int rg = 0; rg < 2; ++rg) {
#pragma unroll
        for (int tt = 0; tt < 4; ++tt)
#pragma unroll
          for (int r = 0; r < 4; ++r)
            acc[rg][tt][r] += rb[(rg * 20 + tt * 4 + r) * 64 + lane];
#pragma unroll
        for (int r = 0; r < 4; ++r) accz[rg][r] += rb[(rg * 20 + 16 + r) * 64 + lane];
      }
    }
    // epilogue: C/D row = q*4+r, col = tt*16+n (verified R2-R10)
#pragma unroll
    for (int rg = 0; rg < 2; ++rg)
#pragma unroll
      for (int r = 0; r < 4; ++r) {
        const float iz = 1.0f / accz[rg][r];
        float* orow = out + (size_t)(i0 + rg * 16 + q * 4 + r) * ND + head * DD + n;
#pragma unroll
        for (int tt = 0; tt < 4; ++tt) orow[tt * 16] = acc[rg][tt][r] * iz;
      }
  }
}

extern "C" void kernel_launch(void* const* d_in, const int* in_sizes, int n_in,
                              void* d_out, int out_size, void* d_ws, size_t ws_size,
                              hipStream_t stream) {
  const float* x = (const float*)d_in[0];
  const int* adj = (const int*)d_in[1];
  const float* W = (const float*)d_in[2];
  const float* a_src = (const float*)d_in[3];
  const float* a_dst = (const float*)d_in[4];
  float* out = (float*)d_out;

  unsigned short* hT = (unsigned short*)d_ws;                     // 2 MB
  float2* Erow = (float2*)(hT + (size_t)NH * DD * CN);            // 128 KB
  float2* Ecol = Erow + (size_t)NH * CN;                          // 128 KB
  unsigned char* mbits8 = (unsigned char*)(Ecol + (size_t)NH * CN);  // 2 MB

  k_pre<<<dim3(256 + CN / 4), 256, 0, stream>>>(adj, mbits8, x, W,
                                                a_src, a_dst, hT, Erow, Ecol);
  k_attn<<<dim3(CN / 32, NH), 512, 0, stream>>>(hT, (const unsigned*)mbits8,
                                                Erow, Ecol, out);
}